// Round 1
// baseline (1818.071 us; speedup 1.0000x reference)
//
#include <hip/hip_runtime.h>
#include <math.h>

// ---------------------------------------------------------------------------
// ChebNet: 3x ChebConv(S=7) + ReLU, then FC(64->1).
// N=50000 nodes, E=800000 edges, F_IN=16, H=64.
// Strategy: build CSR once per call (hist -> scan -> scatter), then
// wave-per-row SpMV (lane = feature) + small LDS-staged GEMM accumulate.
// ---------------------------------------------------------------------------

#define WS_ALIGN(x) (((size_t)(x) + 255) & ~(size_t)255)

__global__ __launch_bounds__(256) void hist_kernel(const int* __restrict__ row, int E,
                                                   int* __restrict__ deg) {
  int i = blockIdx.x * 256 + threadIdx.x;
  if (i < E) atomicAdd(&deg[row[i]], 1);
}

// Single-block inclusive scan over deg[0..n-1].
// Produces row_ptr[0..n] (exclusive at i = row_ptr[i]), cursor[i] = row_ptr[i],
// and dis[i] = deg>0 ? 1/sqrt(deg) : 0.
__global__ __launch_bounds__(1024) void scan_kernel(const int* __restrict__ deg,
                                                    int* __restrict__ row_ptr,
                                                    int* __restrict__ cursor,
                                                    float* __restrict__ dis, int n) {
  __shared__ int wtots[16];
  __shared__ int carry_s;
  int lane = threadIdx.x & 63;
  int wave = threadIdx.x >> 6;
  if (threadIdx.x == 0) { carry_s = 0; row_ptr[0] = 0; }
  __syncthreads();
  for (int base = 0; base < n; base += 1024) {
    int i = base + (int)threadIdx.x;
    int v = (i < n) ? deg[i] : 0;
    int sc = v;
#pragma unroll
    for (int off = 1; off < 64; off <<= 1) {
      int t = __shfl_up(sc, off, 64);
      if (lane >= off) sc += t;
    }
    if (lane == 63) wtots[wave] = sc;
    __syncthreads();
    int wpre = 0;
    for (int w2 = 0; w2 < wave; ++w2) wpre += wtots[w2];
    int carry = carry_s;
    int inc = sc + wpre + carry;
    if (i < n) {
      row_ptr[i + 1] = inc;
      cursor[i] = inc - v;
      dis[i] = (v > 0) ? (1.0f / sqrtf((float)v)) : 0.0f;
    }
    __syncthreads();
    if (threadIdx.x == 1023) carry_s = inc;
    __syncthreads();
  }
}

__global__ __launch_bounds__(256) void scatter_kernel(const int* __restrict__ row,
                                                      const int* __restrict__ col, int E,
                                                      int* __restrict__ cursor,
                                                      const float* __restrict__ dis,
                                                      const float* __restrict__ lamp,
                                                      int* __restrict__ csr_col,
                                                      float* __restrict__ csr_w) {
  int i = blockIdx.x * 256 + threadIdx.x;
  if (i >= E) return;
  int r = row[i], c = col[i];
  int pos = atomicAdd(&cursor[r], 1);
  csr_col[pos] = c;
  csr_w[pos] = -(2.0f / lamp[0]) * dis[r] * dis[c];
}

// xout[i,:] = spmv(xin)[i,:]            (CHEB=false)
// xout[i,:] = 2*spmv(xin)[i,:] - sub[i] (CHEB=true)
// spmv(x)[i] = sum_e w[e]*x[col[e]] + diag*x[i],  diag = 2/lam - 1
// One row per group of F lanes (F=64 -> one wave per row).
template <int F, bool CHEB>
__global__ __launch_bounds__(256) void spmv_kernel(const int* __restrict__ row_ptr,
                                                   const int* __restrict__ csr_col,
                                                   const float* __restrict__ csr_w,
                                                   const float* __restrict__ lamp,
                                                   const float* __restrict__ xin,
                                                   const float* __restrict__ sub,
                                                   float* __restrict__ xout, int n) {
  int i = blockIdx.x * (256 / F) + threadIdx.y;
  if (i >= n) return;
  int f = threadIdx.x;
  float diag = 2.0f / lamp[0] - 1.0f;
  float a = diag * xin[(size_t)i * F + f];
  int s = row_ptr[i], e = row_ptr[i + 1];
  for (int j = s; j < e; ++j) {
    int c = csr_col[j];
    float w = csr_w[j];
    a += w * xin[(size_t)c * F + f];
  }
  float r = CHEB ? (2.0f * a - sub[(size_t)i * F + f]) : a;
  xout[(size_t)i * F + f] = r;
}

// acc[i,h] (+)= sum_k X[i,k] * W[k,h]   (W is FI x 64, staged in LDS)
template <int FI>
__global__ __launch_bounds__(256) void gemm_acc(const float* __restrict__ X,
                                                const float* __restrict__ Wg,
                                                float* __restrict__ acc, int n, int init) {
  __shared__ float Ws[FI * 64];
  int tid = threadIdx.y * 64 + threadIdx.x;
  for (int j = tid; j < FI * 64; j += 256) Ws[j] = Wg[j];
  __syncthreads();
  int i = blockIdx.x * 4 + threadIdx.y;
  if (i >= n) return;
  int h = threadIdx.x;
  const float* xr = X + (size_t)i * FI;
  float a = init ? 0.0f : acc[(size_t)i * 64 + h];
#pragma unroll
  for (int k = 0; k < FI; ++k) a += xr[k] * Ws[k * 64 + h];
  acc[(size_t)i * 64 + h] = a;
}

__global__ __launch_bounds__(256) void bias_relu_kernel(const float* __restrict__ acc,
                                                        const float* __restrict__ b,
                                                        float* __restrict__ out, int total) {
  int idx = blockIdx.x * 256 + threadIdx.x;
  if (idx < total) {
    float v = acc[idx] + b[idx & 63];
    out[idx] = v > 0.0f ? v : 0.0f;
  }
}

__global__ __launch_bounds__(256) void fc_kernel(const float* __restrict__ h,
                                                 const float* __restrict__ Wfc,
                                                 const float* __restrict__ bfc,
                                                 float* __restrict__ out, int n) {
  int i = blockIdx.x * 4 + threadIdx.y;
  if (i >= n) return;
  int l = threadIdx.x;
  float v = h[(size_t)i * 64 + l] * Wfc[l];
#pragma unroll
  for (int off = 32; off > 0; off >>= 1) v += __shfl_down(v, off, 64);
  if (l == 0) out[i] = v + bfc[0];
}

struct Ctx {
  const int* row_ptr;
  const int* csr_col;
  const float* csr_w;
  const float* lamp;
  float* acc;
  int N;
  hipStream_t stream;
};

template <int FI>
static void cheb_layer(const Ctx& c, const float* in, const float* W, float* t1b, float* t2b,
                       float* spare) {
  constexpr int RPB = 256 / FI;
  dim3 bs(FI, RPB);
  int gs = (c.N + RPB - 1) / RPB;
  dim3 gb(64, 4);
  int gg = (c.N + 3) / 4;
  // k = 0
  gemm_acc<FI><<<gg, gb, 0, c.stream>>>(in, W, c.acc, c.N, 1);
  // k = 1
  spmv_kernel<FI, false><<<gs, bs, 0, c.stream>>>(c.row_ptr, c.csr_col, c.csr_w, c.lamp, in,
                                                  nullptr, t1b, c.N);
  gemm_acc<FI><<<gg, gb, 0, c.stream>>>(t1b, W + FI * 64, c.acc, c.N, 0);
  // k = 2..6: Tx2 = 2*spmv(Tx1) - Tx0
  const float* t0 = in;
  float* t1 = t1b;
  float* fr = t2b;
  for (int k = 2; k < 7; ++k) {
    spmv_kernel<FI, true><<<gs, bs, 0, c.stream>>>(c.row_ptr, c.csr_col, c.csr_w, c.lamp, t1, t0,
                                                   fr, c.N);
    gemm_acc<FI><<<gg, gb, 0, c.stream>>>(fr, W + k * FI * 64, c.acc, c.N, 0);
    float* nfr = (k == 2) ? spare : (float*)t0;
    t0 = t1;
    t1 = fr;
    fr = nfr;
  }
}

extern "C" void kernel_launch(void* const* d_in, const int* in_sizes, int n_in, void* d_out,
                              int out_size, void* d_ws, size_t ws_size, hipStream_t stream) {
  const float* x = (const float*)d_in[0];
  const int* ei = (const int*)d_in[1];
  const float* lamp = (const float*)d_in[2];
  const float* W1 = (const float*)d_in[3];
  const float* b1 = (const float*)d_in[4];
  const float* W2 = (const float*)d_in[5];
  const float* b2 = (const float*)d_in[6];
  const float* W3 = (const float*)d_in[7];
  const float* b3 = (const float*)d_in[8];
  const float* Wfc = (const float*)d_in[9];
  const float* bfc = (const float*)d_in[10];

  const int N = in_sizes[0] / 16;
  const int E = in_sizes[1] / 2;
  const int* row = ei;
  const int* col = ei + E;

  // ---- workspace carve ----
  char* p = (char*)d_ws;
  auto alloc = [&](size_t bytes) {
    char* r = p;
    p += WS_ALIGN(bytes);
    return r;
  };
  int* deg = (int*)alloc((size_t)N * 4);
  int* row_ptr = (int*)alloc((size_t)(N + 1) * 4);
  int* cursor = (int*)alloc((size_t)N * 4);
  int* csr_col = (int*)alloc((size_t)E * 4);
  float* csr_w = (float*)alloc((size_t)E * 4);
  float* dis = (float*)alloc((size_t)N * 4);
  float* A = (float*)alloc((size_t)N * 64 * 4);
  float* B = (float*)alloc((size_t)N * 64 * 4);
  float* C = (float*)alloc((size_t)N * 64 * 4);
  float* acc = (float*)alloc((size_t)N * 64 * 4);
  (void)ws_size;
  (void)n_in;
  (void)out_size;

  // ---- CSR build ----
  hipMemsetAsync(deg, 0, (size_t)N * 4, stream);
  hist_kernel<<<(E + 255) / 256, 256, 0, stream>>>(row, E, deg);
  scan_kernel<<<1, 1024, 0, stream>>>(deg, row_ptr, cursor, dis, N);
  scatter_kernel<<<(E + 255) / 256, 256, 0, stream>>>(row, col, E, cursor, dis, lamp, csr_col,
                                                      csr_w);

  Ctx c{row_ptr, csr_col, csr_w, lamp, acc, N, stream};

  // ---- layer 1 (F_IN=16): rotation buffers carved from C (3 x N*16 floats) ----
  float* C0 = C;
  float* C1 = C + (size_t)N * 16;
  float* C2 = C + (size_t)N * 32;
  cheb_layer<16>(c, x, W1, C0, C1, C2);
  bias_relu_kernel<<<(N * 64 + 255) / 256, 256, 0, stream>>>(acc, b1, A, N * 64);

  // ---- layer 2 (64 -> 64): in=A, rotate over {B, C, A} ----
  cheb_layer<64>(c, A, W2, B, C, A);
  bias_relu_kernel<<<(N * 64 + 255) / 256, 256, 0, stream>>>(acc, b2, C, N * 64);

  // ---- layer 3 (64 -> 64): in=C, rotate over {A, B, C} ----
  cheb_layer<64>(c, C, W3, A, B, C);
  bias_relu_kernel<<<(N * 64 + 255) / 256, 256, 0, stream>>>(acc, b3, A, N * 64);

  // ---- final FC 64 -> 1 ----
  fc_kernel<<<(N + 3) / 4, dim3(64, 4), 0, stream>>>(A, Wfc, bfc, (float*)d_out, N);
}

// Round 2
// 1250.697 us; speedup vs baseline: 1.4536x; 1.4536x over previous
//
#include <hip/hip_runtime.h>
#include <math.h>

// ---------------------------------------------------------------------------
// ChebNet: 3x ChebConv(S=7) + ReLU, then FC(64->1).
// N=50000 nodes, E=800000 edges, F_IN=16, H=64.
// R1: latency-focused SpMV (int2-packed CSR, 8-deep predicated gather batches,
// float4 gathers = 4 rows/wave), VGPR-resident-W GEMM (no LDS).
// ---------------------------------------------------------------------------

#define WS_ALIGN(x) (((size_t)(x) + 255) & ~(size_t)255)

__global__ __launch_bounds__(256) void hist_kernel(const int* __restrict__ row, int E,
                                                   int* __restrict__ deg) {
  int i = blockIdx.x * 256 + threadIdx.x;
  if (i < E) atomicAdd(&deg[row[i]], 1);
}

// Single-block inclusive scan over deg[0..n-1].
__global__ __launch_bounds__(1024) void scan_kernel(const int* __restrict__ deg,
                                                    int* __restrict__ row_ptr,
                                                    int* __restrict__ cursor,
                                                    float* __restrict__ dis, int n) {
  __shared__ int wtots[16];
  __shared__ int carry_s;
  int lane = threadIdx.x & 63;
  int wave = threadIdx.x >> 6;
  if (threadIdx.x == 0) { carry_s = 0; row_ptr[0] = 0; }
  __syncthreads();
  for (int base = 0; base < n; base += 1024) {
    int i = base + (int)threadIdx.x;
    int v = (i < n) ? deg[i] : 0;
    int sc = v;
#pragma unroll
    for (int off = 1; off < 64; off <<= 1) {
      int t = __shfl_up(sc, off, 64);
      if (lane >= off) sc += t;
    }
    if (lane == 63) wtots[wave] = sc;
    __syncthreads();
    int wpre = 0;
    for (int w2 = 0; w2 < wave; ++w2) wpre += wtots[w2];
    int carry = carry_s;
    int inc = sc + wpre + carry;
    if (i < n) {
      row_ptr[i + 1] = inc;
      cursor[i] = inc - v;
      dis[i] = (v > 0) ? (1.0f / sqrtf((float)v)) : 0.0f;
    }
    __syncthreads();
    if (threadIdx.x == 1023) carry_s = inc;
    __syncthreads();
  }
}

__global__ __launch_bounds__(256) void scatter_kernel(const int* __restrict__ row,
                                                      const int* __restrict__ col, int E,
                                                      int* __restrict__ cursor,
                                                      const float* __restrict__ dis,
                                                      const float* __restrict__ lamp,
                                                      int2* __restrict__ cw) {
  int i = blockIdx.x * 256 + threadIdx.x;
  if (i >= E) return;
  int r = row[i], c = col[i];
  int pos = atomicAdd(&cursor[r], 1);
  float w = -(2.0f / lamp[0]) * dis[r] * dis[c];
  cw[pos] = make_int2(c, __float_as_int(w));
}

// xout[i,:] = spmv(xin)[i,:]            (CHEB=false)
// xout[i,:] = 2*spmv(xin)[i,:] - sub[i] (CHEB=true)
// float4 lanes: F/4 lanes per row, 1024/F rows per block.
template <int F, bool CHEB>
__global__ __launch_bounds__(256) void spmv_kernel(const int* __restrict__ row_ptr,
                                                   const int2* __restrict__ cw,
                                                   const float* __restrict__ lamp,
                                                   const float* __restrict__ xin,
                                                   const float* __restrict__ sub,
                                                   float* __restrict__ xout, int n) {
  constexpr int LPR = F / 4;    // lanes per row
  constexpr int RPB = 256 / LPR;  // rows per block
  int i = blockIdx.x * RPB + threadIdx.y;
  if (i >= n) return;
  int f4 = threadIdx.x;
  float diag = 2.0f / lamp[0] - 1.0f;
  const float4* xin4 = (const float4*)xin;
  float4 xd = xin4[(size_t)i * LPR + f4];
  float4 a = make_float4(diag * xd.x, diag * xd.y, diag * xd.z, diag * xd.w);
  int s = row_ptr[i], e = row_ptr[i + 1];
  for (int j0 = s; j0 < e; j0 += 8) {
    float4 xv[8];
    float ww[8];
#pragma unroll
    for (int u = 0; u < 8; ++u) {
      int jj = j0 + u;
      bool valid = jj < e;
      int2 p = cw[valid ? jj : s];
      ww[u] = valid ? __int_as_float(p.y) : 0.0f;
      xv[u] = xin4[(size_t)p.x * LPR + f4];
    }
#pragma unroll
    for (int u = 0; u < 8; ++u) {
      a.x += ww[u] * xv[u].x;
      a.y += ww[u] * xv[u].y;
      a.z += ww[u] * xv[u].z;
      a.w += ww[u] * xv[u].w;
    }
  }
  float4 r;
  if (CHEB) {
    const float4* sub4 = (const float4*)sub;
    float4 sv = sub4[(size_t)i * LPR + f4];
    r = make_float4(2.0f * a.x - sv.x, 2.0f * a.y - sv.y, 2.0f * a.z - sv.z,
                    2.0f * a.w - sv.w);
  } else {
    r = a;
  }
  ((float4*)xout)[(size_t)i * LPR + f4] = r;
}

// acc[i,h] (+)= sum_k X[i,k] * W[k,h].  W column in VGPRs, X row via uniform
// float4 broadcast loads, grid-stride so W loads amortize.
template <int FI>
__global__ __launch_bounds__(256) void gemm_acc(const float* __restrict__ X,
                                                const float* __restrict__ Wg,
                                                float* __restrict__ acc, int n, int init) {
  int h = threadIdx.x;   // 0..63 output column
  int wy = threadIdx.y;  // 0..3 row slot
  float wreg[FI];
#pragma unroll
  for (int k = 0; k < FI; ++k) wreg[k] = Wg[k * 64 + h];
  for (int i = blockIdx.x * 4 + wy; i < n; i += gridDim.x * 4) {
    const float4* xr = (const float4*)(X + (size_t)i * FI);
    float a0 = init ? 0.0f : acc[(size_t)i * 64 + h];
    float a1 = 0.0f;
#pragma unroll
    for (int k4 = 0; k4 < FI / 4; ++k4) {
      float4 xv = xr[k4];
      float p = xv.x * wreg[4 * k4] + xv.y * wreg[4 * k4 + 1];
      float q = xv.z * wreg[4 * k4 + 2] + xv.w * wreg[4 * k4 + 3];
      if (k4 & 1) a1 += p + q; else a0 += p + q;
    }
    acc[(size_t)i * 64 + h] = a0 + a1;
  }
}

__global__ __launch_bounds__(256) void bias_relu_kernel(const float* __restrict__ acc,
                                                        const float* __restrict__ b,
                                                        float* __restrict__ out, int n4) {
  int t = blockIdx.x * 256 + threadIdx.x;
  if (t >= n4) return;
  float4 v = ((const float4*)acc)[t];
  float4 bb = ((const float4*)b)[t & 15];
  float4 r;
  r.x = fmaxf(v.x + bb.x, 0.0f);
  r.y = fmaxf(v.y + bb.y, 0.0f);
  r.z = fmaxf(v.z + bb.z, 0.0f);
  r.w = fmaxf(v.w + bb.w, 0.0f);
  ((float4*)out)[t] = r;
}

__global__ __launch_bounds__(256) void fc_kernel(const float* __restrict__ h,
                                                 const float* __restrict__ Wfc,
                                                 const float* __restrict__ bfc,
                                                 float* __restrict__ out, int n) {
  int i = blockIdx.x * 4 + threadIdx.y;
  if (i >= n) return;
  int l = threadIdx.x;
  float v = h[(size_t)i * 64 + l] * Wfc[l];
#pragma unroll
  for (int off = 32; off > 0; off >>= 1) v += __shfl_down(v, off, 64);
  if (l == 0) out[i] = v + bfc[0];
}

struct Ctx {
  const int* row_ptr;
  const int2* cw;
  const float* lamp;
  float* acc;
  int N;
  hipStream_t stream;
};

template <int FI>
static void cheb_layer(const Ctx& c, const float* in, const float* W, float* t1b, float* t2b,
                       float* spare) {
  constexpr int RPB = 1024 / FI;
  dim3 bs(FI / 4, RPB);
  int gs = (c.N + RPB - 1) / RPB;
  dim3 gb(64, 4);
  int gg = 2048;
  // k = 0
  gemm_acc<FI><<<gg, gb, 0, c.stream>>>(in, W, c.acc, c.N, 1);
  // k = 1
  spmv_kernel<FI, false><<<gs, bs, 0, c.stream>>>(c.row_ptr, c.cw, c.lamp, in, nullptr, t1b,
                                                  c.N);
  gemm_acc<FI><<<gg, gb, 0, c.stream>>>(t1b, W + FI * 64, c.acc, c.N, 0);
  // k = 2..6: Tx2 = 2*spmv(Tx1) - Tx0
  const float* t0 = in;
  float* t1 = t1b;
  float* fr = t2b;
  for (int k = 2; k < 7; ++k) {
    spmv_kernel<FI, true><<<gs, bs, 0, c.stream>>>(c.row_ptr, c.cw, c.lamp, t1, t0, fr, c.N);
    gemm_acc<FI><<<gg, gb, 0, c.stream>>>(fr, W + k * FI * 64, c.acc, c.N, 0);
    float* nfr = (k == 2) ? spare : (float*)t0;
    t0 = t1;
    t1 = fr;
    fr = nfr;
  }
}

extern "C" void kernel_launch(void* const* d_in, const int* in_sizes, int n_in, void* d_out,
                              int out_size, void* d_ws, size_t ws_size, hipStream_t stream) {
  const float* x = (const float*)d_in[0];
  const int* ei = (const int*)d_in[1];
  const float* lamp = (const float*)d_in[2];
  const float* W1 = (const float*)d_in[3];
  const float* b1 = (const float*)d_in[4];
  const float* W2 = (const float*)d_in[5];
  const float* b2 = (const float*)d_in[6];
  const float* W3 = (const float*)d_in[7];
  const float* b3 = (const float*)d_in[8];
  const float* Wfc = (const float*)d_in[9];
  const float* bfc = (const float*)d_in[10];

  const int N = in_sizes[0] / 16;
  const int E = in_sizes[1] / 2;
  const int* row = ei;
  const int* col = ei + E;

  // ---- workspace carve ----
  char* p = (char*)d_ws;
  auto alloc = [&](size_t bytes) {
    char* r = p;
    p += WS_ALIGN(bytes);
    return r;
  };
  int* deg = (int*)alloc((size_t)N * 4);
  int* row_ptr = (int*)alloc((size_t)(N + 1) * 4);
  int* cursor = (int*)alloc((size_t)N * 4);
  int2* cw = (int2*)alloc((size_t)E * 8);
  float* dis = (float*)alloc((size_t)N * 4);
  float* A = (float*)alloc((size_t)N * 64 * 4);
  float* B = (float*)alloc((size_t)N * 64 * 4);
  float* C = (float*)alloc((size_t)N * 64 * 4);
  float* acc = (float*)alloc((size_t)N * 64 * 4);
  (void)ws_size;
  (void)n_in;
  (void)out_size;

  // ---- CSR build ----
  hipMemsetAsync(deg, 0, (size_t)N * 4, stream);
  hist_kernel<<<(E + 255) / 256, 256, 0, stream>>>(row, E, deg);
  scan_kernel<<<1, 1024, 0, stream>>>(deg, row_ptr, cursor, dis, N);
  scatter_kernel<<<(E + 255) / 256, 256, 0, stream>>>(row, col, E, cursor, dis, lamp, cw);

  Ctx c{row_ptr, cw, lamp, acc, N, stream};

  // ---- layer 1 (F_IN=16): rotation buffers carved from C (3 x N*16 floats) ----
  float* C0 = C;
  float* C1 = C + (size_t)N * 16;
  float* C2 = C + (size_t)N * 32;
  cheb_layer<16>(c, x, W1, C0, C1, C2);
  bias_relu_kernel<<<(N * 16 + 255) / 256, 256, 0, stream>>>(acc, b1, A, N * 16);

  // ---- layer 2 (64 -> 64): in=A, rotate over {B, C, A} ----
  cheb_layer<64>(c, A, W2, B, C, A);
  bias_relu_kernel<<<(N * 16 + 255) / 256, 256, 0, stream>>>(acc, b2, C, N * 16);

  // ---- layer 3 (64 -> 64): in=C, rotate over {A, B, C} ----
  cheb_layer<64>(c, C, W3, A, B, C);
  bias_relu_kernel<<<(N * 16 + 255) / 256, 256, 0, stream>>>(acc, b3, A, N * 16);

  // ---- final FC 64 -> 1 ----
  fc_kernel<<<(N + 3) / 4, dim3(64, 4), 0, stream>>>(A, Wfc, bfc, (float*)d_out, N);
}

// Round 3
// 707.474 us; speedup vs baseline: 2.5698x; 1.7678x over previous
//
#include <hip/hip_runtime.h>
#include <math.h>

// ---------------------------------------------------------------------------
// ChebNet: 3x ChebConv(S=7) + ReLU, then FC(64->1).
// N=50000 nodes, E=800000 edges, F_IN=16, H=64.
// R2: hierarchical scan; spmv with coalesced cw load + shfl broadcast
// (16 gathers in flight); GEMM fused into spmv epilogue via per-wave LDS
// row staging (kills all standalone gemm kernels); layer-3 bias+relu+FC fused.
// ---------------------------------------------------------------------------

#define WS_ALIGN(x) (((size_t)(x) + 255) & ~(size_t)255)

__global__ __launch_bounds__(256) void hist_kernel(const int* __restrict__ row, int E,
                                                   int* __restrict__ deg) {
  int i = blockIdx.x * 256 + threadIdx.x;
  if (i < E) atomicAdd(&deg[row[i]], 1);
}

// ---- hierarchical scan: block sums -> scan sums -> per-block rescan ----
__global__ __launch_bounds__(256) void scan_sum_kernel(const int* __restrict__ deg,
                                                       int* __restrict__ bsum, int n) {
  int base = blockIdx.x * 1024 + threadIdx.x;
  int v = 0;
#pragma unroll
  for (int u = 0; u < 4; ++u) {
    int i = base + u * 256;
    if (i < n) v += deg[i];
  }
#pragma unroll
  for (int off = 32; off > 0; off >>= 1) v += __shfl_down(v, off, 64);
  __shared__ int ws[4];
  int lane = threadIdx.x & 63, wave = threadIdx.x >> 6;
  if (lane == 0) ws[wave] = v;
  __syncthreads();
  if (threadIdx.x == 0) bsum[blockIdx.x] = ws[0] + ws[1] + ws[2] + ws[3];
}

// single wave scans the (<=64) block sums to exclusive form
__global__ __launch_bounds__(64) void scan_bsum_kernel(int* __restrict__ bsum, int nb) {
  int t = threadIdx.x;
  int v = (t < nb) ? bsum[t] : 0;
  int sc = v;
#pragma unroll
  for (int off = 1; off < 64; off <<= 1) {
    int tv = __shfl_up(sc, off, 64);
    if (t >= off) sc += tv;
  }
  if (t < nb) bsum[t] = sc - v;
}

__global__ __launch_bounds__(256) void scan_out_kernel(const int* __restrict__ deg,
                                                       const int* __restrict__ bsum,
                                                       int* __restrict__ row_ptr,
                                                       int* __restrict__ cursor,
                                                       float* __restrict__ dis, int n) {
  int base = blockIdx.x * 1024 + threadIdx.x * 4;
  int loc[4];
  int s = 0;
#pragma unroll
  for (int u = 0; u < 4; ++u) {
    int i = base + u;
    loc[u] = (i < n) ? deg[i] : 0;
    s += loc[u];
  }
  int lane = threadIdx.x & 63, wave = threadIdx.x >> 6;
  int sc = s;
#pragma unroll
  for (int off = 1; off < 64; off <<= 1) {
    int tv = __shfl_up(sc, off, 64);
    if (lane >= off) sc += tv;
  }
  __shared__ int wtot[4];
  if (lane == 63) wtot[wave] = sc;
  __syncthreads();
  int pre = sc - s + bsum[blockIdx.x];
  for (int w = 0; w < wave; ++w) pre += wtot[w];
  if (blockIdx.x == 0 && threadIdx.x == 0) row_ptr[0] = 0;
  int running = pre;
#pragma unroll
  for (int u = 0; u < 4; ++u) {
    int i = base + u;
    if (i < n) {
      cursor[i] = running;
      dis[i] = (loc[u] > 0) ? (1.0f / sqrtf((float)loc[u])) : 0.0f;
      running += loc[u];
      row_ptr[i + 1] = running;
    }
  }
}

__global__ __launch_bounds__(256) void scatter_kernel(const int* __restrict__ row,
                                                      const int* __restrict__ col, int E,
                                                      int* __restrict__ cursor,
                                                      const float* __restrict__ dis,
                                                      const float* __restrict__ lamp,
                                                      int2* __restrict__ cw) {
  int i = blockIdx.x * 256 + threadIdx.x;
  if (i >= E) return;
  int r = row[i], c = col[i];
  int pos = atomicAdd(&cursor[r], 1);
  float w = -(2.0f / lamp[0]) * dis[r] * dis[c];
  cw[pos] = make_int2(c, __float_as_int(w));
}

// ---------------------------------------------------------------------------
// Fused SpMV + GEMM-accumulate.
// MODE 0 (k=1): r = spmv(xin);            acc[i,:]  = xin[i,:]@W0 + r@W1
// MODE 1 (k>=2): r = 2*spmv(xin) - sub;   acc[i,:] += r@Wk
// WRITE_OUT=false for the last k (Tx never consumed again).
// Row of F features held by F/4 lanes as float4. 16-edge batches: coalesced
// cw load + shfl broadcast -> 16 gathers in flight per row.
// Epilogue: stage row in per-wave LDS (padded), W staged in LDS per block.
// ---------------------------------------------------------------------------
template <int F, int MODE, bool WRITE_OUT>
__global__ __launch_bounds__(256) void spmv_fused(
    const int* __restrict__ row_ptr, const int2* __restrict__ cw,
    const float* __restrict__ lamp, const float* __restrict__ xin,
    const float* __restrict__ sub, float* __restrict__ xout, float* __restrict__ acc,
    const float* __restrict__ Wg, int n) {
  constexpr int LPR = F / 4;       // lanes per row
  constexpr int RPB = 256 / LPR;   // rows per block
  constexpr int EPL = 16 / LPR;    // cw entries loaded per lane per 16-edge batch
  constexpr int NW = (MODE == 0) ? 2 : 1;
  __shared__ float Ws[NW * F * 64];
  __shared__ float r_lds[RPB][F + 4];

  int f4 = threadIdx.x;
  int tid = threadIdx.y * LPR + f4;
  // cooperative W stage (W0[,W1] contiguous in input layout S x F x 64)
  for (int j = tid; j < NW * F * 16; j += 256)
    ((float4*)Ws)[j] = ((const float4*)Wg)[j];
  __syncthreads();

  int i = blockIdx.x * RPB + threadIdx.y;
  if (i >= n) return;
  int lane = tid & 63;
  int grpbase = lane - f4;
  float diag = 2.0f / lamp[0] - 1.0f;
  const float4* xin4 = (const float4*)xin;
  float4 xd = xin4[(size_t)i * LPR + f4];
  float4 a = make_float4(diag * xd.x, diag * xd.y, diag * xd.z, diag * xd.w);
  int s = row_ptr[i], e = row_ptr[i + 1];

  for (int j0 = s; j0 < e; j0 += 16) {
    int2 pv[EPL];
#pragma unroll
    for (int u = 0; u < EPL; ++u) {
      int jj = j0 + f4 * EPL + u;
      pv[u] = cw[jj < e ? jj : (e - 1)];
    }
    float4 xv[16];
    float ww[16];
#pragma unroll
    for (int u = 0; u < 16; ++u) {
      int cu = __shfl(pv[u % EPL].x, grpbase + u / EPL, 64);
      int wu = __shfl(pv[u % EPL].y, grpbase + u / EPL, 64);
      bool valid = (j0 + u) < e;
      ww[u] = valid ? __int_as_float(wu) : 0.0f;
      int ad = valid ? cu : i;
      xv[u] = xin4[(size_t)ad * LPR + f4];
    }
#pragma unroll
    for (int u = 0; u < 16; ++u) {
      a.x += ww[u] * xv[u].x;
      a.y += ww[u] * xv[u].y;
      a.z += ww[u] * xv[u].z;
      a.w += ww[u] * xv[u].w;
    }
  }

  float4 r;
  if (MODE == 1) {
    const float4* sub4 = (const float4*)sub;
    float4 sv = sub4[(size_t)i * LPR + f4];
    r = make_float4(2.0f * a.x - sv.x, 2.0f * a.y - sv.y, 2.0f * a.z - sv.z,
                    2.0f * a.w - sv.w);
  } else {
    r = a;
  }
  if (WRITE_OUT) ((float4*)xout)[(size_t)i * LPR + f4] = r;

  float* rrow = r_lds[threadIdx.y];

  if constexpr (F == 64) {
    // lane owns output cols 4*f4 .. 4*f4+3
    float4 acc4;
    auto epil = [&](const float4& vec, const float* W) {
      *(float4*)&rrow[f4 * 4] = vec;  // within-wave staging, no barrier needed
#pragma unroll
      for (int k4 = 0; k4 < 16; ++k4) {
        float4 rv = *(const float4*)&rrow[k4 * 4];
        const float* wb = &W[(k4 * 4) * 64 + 4 * f4];
        float4 w0 = *(const float4*)&wb[0];
        float4 w1 = *(const float4*)&wb[64];
        float4 w2 = *(const float4*)&wb[128];
        float4 w3 = *(const float4*)&wb[192];
        acc4.x += rv.x * w0.x + rv.y * w1.x + rv.z * w2.x + rv.w * w3.x;
        acc4.y += rv.x * w0.y + rv.y * w1.y + rv.z * w2.y + rv.w * w3.y;
        acc4.z += rv.x * w0.z + rv.y * w1.z + rv.z * w2.z + rv.w * w3.z;
        acc4.w += rv.x * w0.w + rv.y * w1.w + rv.z * w2.w + rv.w * w3.w;
      }
    };
    float4* accp = (float4*)acc + (size_t)i * 16 + f4;
    if (MODE == 0) {
      acc4 = make_float4(0.f, 0.f, 0.f, 0.f);
      epil(xd, Ws);
      epil(r, Ws + F * 64);
    } else {
      acc4 = *accp;
      epil(r, Ws);
    }
    *accp = acc4;
  } else {
    // F == 16: lane owns output cols f4*16 .. f4*16+15 (4 float4)
    float4 o[4];
    auto epil = [&](const float4& vec, const float* W) {
      *(float4*)&rrow[f4 * 4] = vec;
#pragma unroll
      for (int k4 = 0; k4 < 4; ++k4) {
        float4 rv = *(const float4*)&rrow[k4 * 4];
#pragma unroll
        for (int kk = 0; kk < 4; ++kk) {
          float rk = (kk == 0) ? rv.x : (kk == 1) ? rv.y : (kk == 2) ? rv.z : rv.w;
          const float4* wr = (const float4*)&W[(k4 * 4 + kk) * 64 + f4 * 16];
          float4 w0 = wr[0], w1 = wr[1], w2 = wr[2], w3 = wr[3];
          o[0].x += rk * w0.x; o[0].y += rk * w0.y; o[0].z += rk * w0.z; o[0].w += rk * w0.w;
          o[1].x += rk * w1.x; o[1].y += rk * w1.y; o[1].z += rk * w1.z; o[1].w += rk * w1.w;
          o[2].x += rk * w2.x; o[2].y += rk * w2.y; o[2].z += rk * w2.z; o[2].w += rk * w2.w;
          o[3].x += rk * w3.x; o[3].y += rk * w3.y; o[3].z += rk * w3.z; o[3].w += rk * w3.w;
        }
      }
    };
    float4* accp = (float4*)acc + (size_t)i * 16 + f4 * 4;
    if (MODE == 0) {
#pragma unroll
      for (int t = 0; t < 4; ++t) o[t] = make_float4(0.f, 0.f, 0.f, 0.f);
      epil(xd, Ws);
      epil(r, Ws + F * 64);
    } else {
#pragma unroll
      for (int t = 0; t < 4; ++t) o[t] = accp[t];
      epil(r, Ws);
    }
#pragma unroll
    for (int t = 0; t < 4; ++t) accp[t] = o[t];
  }
}

__global__ __launch_bounds__(256) void bias_relu_kernel(const float* __restrict__ acc,
                                                        const float* __restrict__ b,
                                                        float* __restrict__ out, int n4) {
  int t = blockIdx.x * 256 + threadIdx.x;
  if (t >= n4) return;
  float4 v = ((const float4*)acc)[t];
  float4 bb = ((const float4*)b)[t & 15];
  float4 r;
  r.x = fmaxf(v.x + bb.x, 0.0f);
  r.y = fmaxf(v.y + bb.y, 0.0f);
  r.z = fmaxf(v.z + bb.z, 0.0f);
  r.w = fmaxf(v.w + bb.w, 0.0f);
  ((float4*)out)[t] = r;
}

// layer-3 epilogue: out[i] = sum_h relu(acc[i,h]+b[h]) * Wfc[h] + bfc
__global__ __launch_bounds__(256) void fc_fused_kernel(const float* __restrict__ acc,
                                                       const float* __restrict__ b,
                                                       const float* __restrict__ Wfc,
                                                       const float* __restrict__ bfc,
                                                       float* __restrict__ out, int n) {
  int i = blockIdx.x * 4 + threadIdx.y;
  if (i >= n) return;
  int l = threadIdx.x;
  float v = fmaxf(acc[(size_t)i * 64 + l] + b[l], 0.0f) * Wfc[l];
#pragma unroll
  for (int off = 32; off > 0; off >>= 1) v += __shfl_down(v, off, 64);
  if (l == 0) out[i] = v + bfc[0];
}

struct Ctx {
  const int* row_ptr;
  const int2* cw;
  const float* lamp;
  float* acc;
  int N;
  hipStream_t stream;
};

template <int F>
static void cheb_layer(const Ctx& c, const float* in, const float* W, float* t1b, float* t2b,
                       float* spare) {
  constexpr int RPB = 1024 / F;
  dim3 bs(F / 4, RPB);
  int gs = (c.N + RPB - 1) / RPB;
  // k=0,1 fused: Tx1 = spmv(in); acc = in@W0 + Tx1@W1
  spmv_fused<F, 0, true><<<gs, bs, 0, c.stream>>>(c.row_ptr, c.cw, c.lamp, in, nullptr, t1b,
                                                  c.acc, W, c.N);
  const float* t0 = in;
  float* t1 = t1b;
  float* fr = t2b;
  for (int k = 2; k < 7; ++k) {
    if (k < 6)
      spmv_fused<F, 1, true><<<gs, bs, 0, c.stream>>>(c.row_ptr, c.cw, c.lamp, t1, t0, fr,
                                                      c.acc, W + k * F * 64, c.N);
    else
      spmv_fused<F, 1, false><<<gs, bs, 0, c.stream>>>(c.row_ptr, c.cw, c.lamp, t1, t0, fr,
                                                       c.acc, W + k * F * 64, c.N);
    float* nfr = (k == 2) ? spare : (float*)t0;
    t0 = t1;
    t1 = fr;
    fr = nfr;
  }
}

extern "C" void kernel_launch(void* const* d_in, const int* in_sizes, int n_in, void* d_out,
                              int out_size, void* d_ws, size_t ws_size, hipStream_t stream) {
  const float* x = (const float*)d_in[0];
  const int* ei = (const int*)d_in[1];
  const float* lamp = (const float*)d_in[2];
  const float* W1 = (const float*)d_in[3];
  const float* b1 = (const float*)d_in[4];
  const float* W2 = (const float*)d_in[5];
  const float* b2 = (const float*)d_in[6];
  const float* W3 = (const float*)d_in[7];
  const float* b3 = (const float*)d_in[8];
  const float* Wfc = (const float*)d_in[9];
  const float* bfc = (const float*)d_in[10];

  const int N = in_sizes[0] / 16;
  const int E = in_sizes[1] / 2;
  const int* row = ei;
  const int* col = ei + E;

  // ---- workspace carve ----
  char* p = (char*)d_ws;
  auto alloc = [&](size_t bytes) {
    char* r = p;
    p += WS_ALIGN(bytes);
    return r;
  };
  int* deg = (int*)alloc((size_t)N * 4);
  int* row_ptr = (int*)alloc((size_t)(N + 1) * 4);
  int* cursor = (int*)alloc((size_t)N * 4);
  int2* cw = (int2*)alloc((size_t)E * 8);
  float* dis = (float*)alloc((size_t)N * 4);
  int* bsum = (int*)alloc(256 * 4);
  float* A = (float*)alloc((size_t)N * 64 * 4);
  float* B = (float*)alloc((size_t)N * 64 * 4);
  float* C = (float*)alloc((size_t)N * 64 * 4);
  float* acc = (float*)alloc((size_t)N * 64 * 4);
  (void)ws_size;
  (void)n_in;
  (void)out_size;

  // ---- CSR build ----
  hipMemsetAsync(deg, 0, (size_t)N * 4, stream);
  hist_kernel<<<(E + 255) / 256, 256, 0, stream>>>(row, E, deg);
  int nb = (N + 1023) / 1024;  // <= 64 for N <= 65536
  scan_sum_kernel<<<nb, 256, 0, stream>>>(deg, bsum, N);
  scan_bsum_kernel<<<1, 64, 0, stream>>>(bsum, nb);
  scan_out_kernel<<<nb, 256, 0, stream>>>(deg, bsum, row_ptr, cursor, dis, N);
  scatter_kernel<<<(E + 255) / 256, 256, 0, stream>>>(row, col, E, cursor, dis, lamp, cw);

  Ctx c{row_ptr, cw, lamp, acc, N, stream};

  // ---- layer 1 (F_IN=16): rotation buffers carved from C (3 x N*16 floats) ----
  float* C0 = C;
  float* C1 = C + (size_t)N * 16;
  float* C2 = C + (size_t)N * 32;
  cheb_layer<16>(c, x, W1, C0, C1, C2);
  bias_relu_kernel<<<(N * 16 + 255) / 256, 256, 0, stream>>>(acc, b1, A, N * 16);

  // ---- layer 2 (64 -> 64): in=A, rotate over {B, C, A} ----
  cheb_layer<64>(c, A, W2, B, C, A);
  bias_relu_kernel<<<(N * 16 + 255) / 256, 256, 0, stream>>>(acc, b2, C, N * 16);

  // ---- layer 3 (64 -> 64): in=C, rotate over {A, B, C} ----
  cheb_layer<64>(c, C, W3, A, B, C);

  // ---- fused bias+relu+FC ----
  fc_fused_kernel<<<(N + 3) / 4, dim3(64, 4), 0, stream>>>(acc, b3, Wfc, bfc, (float*)d_out,
                                                           N);
}

// Round 4
// 566.743 us; speedup vs baseline: 3.2079x; 1.2483x over previous
//
#include <hip/hip_runtime.h>
#include <math.h>

// ---------------------------------------------------------------------------
// ChebNet: 3x ChebConv(S=7) + ReLU, then FC(64->1).
// N=50000 nodes, E=800000 edges, F_IN=16, H=64.
// R3: fp16 feature buffers (halves the dominant gather traffic), cw packed to
// 4B/edge (col<<16 | fp16 weight; requires N < 65536), fp32 accumulation
// everywhere. CSR build + fused spmv/gemm structure from R2.
// ---------------------------------------------------------------------------

#define WS_ALIGN(x) (((size_t)(x) + 255) & ~(size_t)255)

__device__ inline float h2f_bits(unsigned int b) {
  unsigned short s = (unsigned short)(b & 0xffffu);
  _Float16 h;
  __builtin_memcpy(&h, &s, 2);
  return (float)h;
}
__device__ inline unsigned short f2h_bits(float f) {
  _Float16 h = (_Float16)f;
  unsigned short s;
  __builtin_memcpy(&s, &h, 2);
  return s;
}
union H4 {
  ushort4 u;
  _Float16 h[4];
};

__global__ __launch_bounds__(256) void hist_kernel(const int* __restrict__ row, int E,
                                                   int* __restrict__ deg) {
  int i = blockIdx.x * 256 + threadIdx.x;
  if (i < E) atomicAdd(&deg[row[i]], 1);
}

// ---- hierarchical scan: block sums -> scan sums -> per-block rescan ----
__global__ __launch_bounds__(256) void scan_sum_kernel(const int* __restrict__ deg,
                                                       int* __restrict__ bsum, int n) {
  int base = blockIdx.x * 1024 + threadIdx.x;
  int v = 0;
#pragma unroll
  for (int u = 0; u < 4; ++u) {
    int i = base + u * 256;
    if (i < n) v += deg[i];
  }
#pragma unroll
  for (int off = 32; off > 0; off >>= 1) v += __shfl_down(v, off, 64);
  __shared__ int ws[4];
  int lane = threadIdx.x & 63, wave = threadIdx.x >> 6;
  if (lane == 0) ws[wave] = v;
  __syncthreads();
  if (threadIdx.x == 0) bsum[blockIdx.x] = ws[0] + ws[1] + ws[2] + ws[3];
}

__global__ __launch_bounds__(64) void scan_bsum_kernel(int* __restrict__ bsum, int nb) {
  int t = threadIdx.x;
  int v = (t < nb) ? bsum[t] : 0;
  int sc = v;
#pragma unroll
  for (int off = 1; off < 64; off <<= 1) {
    int tv = __shfl_up(sc, off, 64);
    if (t >= off) sc += tv;
  }
  if (t < nb) bsum[t] = sc - v;
}

__global__ __launch_bounds__(256) void scan_out_kernel(const int* __restrict__ deg,
                                                       const int* __restrict__ bsum,
                                                       int* __restrict__ row_ptr,
                                                       int* __restrict__ cursor,
                                                       float* __restrict__ dis, int n) {
  int base = blockIdx.x * 1024 + threadIdx.x * 4;
  int loc[4];
  int s = 0;
#pragma unroll
  for (int u = 0; u < 4; ++u) {
    int i = base + u;
    loc[u] = (i < n) ? deg[i] : 0;
    s += loc[u];
  }
  int lane = threadIdx.x & 63, wave = threadIdx.x >> 6;
  int sc = s;
#pragma unroll
  for (int off = 1; off < 64; off <<= 1) {
    int tv = __shfl_up(sc, off, 64);
    if (lane >= off) sc += tv;
  }
  __shared__ int wtot[4];
  if (lane == 63) wtot[wave] = sc;
  __syncthreads();
  int pre = sc - s + bsum[blockIdx.x];
  for (int w = 0; w < wave; ++w) pre += wtot[w];
  if (blockIdx.x == 0 && threadIdx.x == 0) row_ptr[0] = 0;
  int running = pre;
#pragma unroll
  for (int u = 0; u < 4; ++u) {
    int i = base + u;
    if (i < n) {
      cursor[i] = running;
      dis[i] = (loc[u] > 0) ? (1.0f / sqrtf((float)loc[u])) : 0.0f;
      running += loc[u];
      row_ptr[i + 1] = running;
    }
  }
}

// cw entry: (col << 16) | fp16_bits(w).  Requires N < 65536.
__global__ __launch_bounds__(256) void scatter_kernel(const int* __restrict__ row,
                                                      const int* __restrict__ col, int E,
                                                      int* __restrict__ cursor,
                                                      const float* __restrict__ dis,
                                                      const float* __restrict__ lamp,
                                                      unsigned int* __restrict__ cw) {
  int i = blockIdx.x * 256 + threadIdx.x;
  if (i >= E) return;
  int r = row[i], c = col[i];
  int pos = atomicAdd(&cursor[r], 1);
  float w = -(2.0f / lamp[0]) * dis[r] * dis[c];
  cw[pos] = ((unsigned int)c << 16) | (unsigned int)f2h_bits(w);
}

__global__ __launch_bounds__(256) void f32_to_f16_kernel(const float* __restrict__ in,
                                                         ushort* __restrict__ out, int n4) {
  int t = blockIdx.x * 256 + threadIdx.x;
  if (t >= n4) return;
  float4 v = ((const float4*)in)[t];
  ushort4 o;
  o.x = f2h_bits(v.x);
  o.y = f2h_bits(v.y);
  o.z = f2h_bits(v.z);
  o.w = f2h_bits(v.w);
  ((ushort4*)out)[t] = o;
}

// ---------------------------------------------------------------------------
// Fused SpMV + GEMM-accumulate, fp16 features / fp32 accumulate.
// MODE 0 (k=1): r = spmv(xin);            acc[i,:]  = xin[i,:]@W0 + r@W1
// MODE 1 (k>=2): r = 2*spmv(xin) - sub;   acc[i,:] += r@Wk
// WRITE_OUT=false for the last k.
// ---------------------------------------------------------------------------
template <int F, int MODE, bool WRITE_OUT>
__global__ __launch_bounds__(256) void spmv_fused(
    const int* __restrict__ row_ptr, const unsigned int* __restrict__ cw,
    const float* __restrict__ lamp, const ushort* __restrict__ xin,
    const ushort* __restrict__ sub, ushort* __restrict__ xout, float* __restrict__ acc,
    const float* __restrict__ Wg, int n) {
  constexpr int LPR = F / 4;      // lanes per row
  constexpr int RPB = 256 / LPR;  // rows per block
  constexpr int EPL = 16 / LPR;   // cw entries per lane per 16-edge batch
  constexpr int NW = (MODE == 0) ? 2 : 1;
  __shared__ float Ws[NW * F * 64];
  __shared__ float r_lds[RPB][F + 4];

  int f4 = threadIdx.x;
  int tid = threadIdx.y * LPR + f4;
  for (int j = tid; j < NW * F * 16; j += 256)
    ((float4*)Ws)[j] = ((const float4*)Wg)[j];
  __syncthreads();

  int i = blockIdx.x * RPB + threadIdx.y;
  if (i >= n) return;
  int lane = tid & 63;
  int grpbase = lane - f4;
  float diag = 2.0f / lamp[0] - 1.0f;
  const ushort4* xin4 = (const ushort4*)xin;
  H4 xdv;
  xdv.u = xin4[(size_t)i * LPR + f4];
  float4 xd = make_float4((float)xdv.h[0], (float)xdv.h[1], (float)xdv.h[2], (float)xdv.h[3]);
  float4 a = make_float4(diag * xd.x, diag * xd.y, diag * xd.z, diag * xd.w);
  int s = row_ptr[i], e = row_ptr[i + 1];

  for (int j0 = s; j0 < e; j0 += 16) {
    unsigned int pv[EPL];
#pragma unroll
    for (int u = 0; u < EPL; ++u) {
      int jj = j0 + f4 * EPL + u;
      pv[u] = cw[jj < e ? jj : (e - 1)];
    }
    H4 xv[16];
    float ww[16];
#pragma unroll
    for (int u = 0; u < 16; ++u) {
      unsigned int pu =
          (unsigned int)__shfl((int)pv[u % EPL], grpbase + u / EPL, 64);
      bool valid = (j0 + u) < e;
      ww[u] = valid ? h2f_bits(pu) : 0.0f;
      int ad = valid ? (int)(pu >> 16) : i;
      xv[u].u = xin4[(size_t)ad * LPR + f4];
    }
#pragma unroll
    for (int u = 0; u < 16; ++u) {
      a.x += ww[u] * (float)xv[u].h[0];
      a.y += ww[u] * (float)xv[u].h[1];
      a.z += ww[u] * (float)xv[u].h[2];
      a.w += ww[u] * (float)xv[u].h[3];
    }
  }

  float4 r;
  if (MODE == 1) {
    H4 sv;
    sv.u = ((const ushort4*)sub)[(size_t)i * LPR + f4];
    r = make_float4(2.0f * a.x - (float)sv.h[0], 2.0f * a.y - (float)sv.h[1],
                    2.0f * a.z - (float)sv.h[2], 2.0f * a.w - (float)sv.h[3]);
  } else {
    r = a;
  }
  if (WRITE_OUT) {
    ushort4 o;
    o.x = f2h_bits(r.x);
    o.y = f2h_bits(r.y);
    o.z = f2h_bits(r.z);
    o.w = f2h_bits(r.w);
    ((ushort4*)xout)[(size_t)i * LPR + f4] = o;
  }

  float* rrow = r_lds[threadIdx.y];

  if constexpr (F == 64) {
    float4 acc4;
    auto epil = [&](const float4& vec, const float* W) {
      *(float4*)&rrow[f4 * 4] = vec;  // within-wave staging, no barrier needed
#pragma unroll
      for (int k4 = 0; k4 < 16; ++k4) {
        float4 rv = *(const float4*)&rrow[k4 * 4];
        const float* wb = &W[(k4 * 4) * 64 + 4 * f4];
        float4 w0 = *(const float4*)&wb[0];
        float4 w1 = *(const float4*)&wb[64];
        float4 w2 = *(const float4*)&wb[128];
        float4 w3 = *(const float4*)&wb[192];
        acc4.x += rv.x * w0.x + rv.y * w1.x + rv.z * w2.x + rv.w * w3.x;
        acc4.y += rv.x * w0.y + rv.y * w1.y + rv.z * w2.y + rv.w * w3.y;
        acc4.z += rv.x * w0.z + rv.y * w1.z + rv.z * w2.z + rv.w * w3.z;
        acc4.w += rv.x * w0.w + rv.y * w1.w + rv.z * w2.w + rv.w * w3.w;
      }
    };
    float4* accp = (float4*)acc + (size_t)i * 16 + f4;
    if (MODE == 0) {
      acc4 = make_float4(0.f, 0.f, 0.f, 0.f);
      epil(xd, Ws);
      epil(r, Ws + F * 64);
    } else {
      acc4 = *accp;
      epil(r, Ws);
    }
    *accp = acc4;
  } else {
    // F == 16: lane owns output cols f4*16 .. f4*16+15
    float4 o[4];
    auto epil = [&](const float4& vec, const float* W) {
      *(float4*)&rrow[f4 * 4] = vec;
#pragma unroll
      for (int k4 = 0; k4 < 4; ++k4) {
        float4 rv = *(const float4*)&rrow[k4 * 4];
#pragma unroll
        for (int kk = 0; kk < 4; ++kk) {
          float rk = (kk == 0) ? rv.x : (kk == 1) ? rv.y : (kk == 2) ? rv.z : rv.w;
          const float4* wr = (const float4*)&W[(k4 * 4 + kk) * 64 + f4 * 16];
          float4 w0 = wr[0], w1 = wr[1], w2 = wr[2], w3 = wr[3];
          o[0].x += rk * w0.x; o[0].y += rk * w0.y; o[0].z += rk * w0.z; o[0].w += rk * w0.w;
          o[1].x += rk * w1.x; o[1].y += rk * w1.y; o[1].z += rk * w1.z; o[1].w += rk * w1.w;
          o[2].x += rk * w2.x; o[2].y += rk * w2.y; o[2].z += rk * w2.z; o[2].w += rk * w2.w;
          o[3].x += rk * w3.x; o[3].y += rk * w3.y; o[3].z += rk * w3.z; o[3].w += rk * w3.w;
        }
      }
    };
    float4* accp = (float4*)acc + (size_t)i * 16 + f4 * 4;
    if (MODE == 0) {
#pragma unroll
      for (int t = 0; t < 4; ++t) o[t] = make_float4(0.f, 0.f, 0.f, 0.f);
      epil(xd, Ws);
      epil(r, Ws + F * 64);
    } else {
#pragma unroll
      for (int t = 0; t < 4; ++t) o[t] = accp[t];
      epil(r, Ws);
    }
#pragma unroll
    for (int t = 0; t < 4; ++t) accp[t] = o[t];
  }
}

// acc fp32 -> h fp16 with bias+relu
__global__ __launch_bounds__(256) void bias_relu_kernel(const float* __restrict__ acc,
                                                        const float* __restrict__ b,
                                                        ushort* __restrict__ out, int n4) {
  int t = blockIdx.x * 256 + threadIdx.x;
  if (t >= n4) return;
  float4 v = ((const float4*)acc)[t];
  float4 bb = ((const float4*)b)[t & 15];
  ushort4 o;
  o.x = f2h_bits(fmaxf(v.x + bb.x, 0.0f));
  o.y = f2h_bits(fmaxf(v.y + bb.y, 0.0f));
  o.z = f2h_bits(fmaxf(v.z + bb.z, 0.0f));
  o.w = f2h_bits(fmaxf(v.w + bb.w, 0.0f));
  ((ushort4*)out)[t] = o;
}

// layer-3 epilogue: out[i] = sum_h relu(acc[i,h]+b[h]) * Wfc[h] + bfc
__global__ __launch_bounds__(256) void fc_fused_kernel(const float* __restrict__ acc,
                                                       const float* __restrict__ b,
                                                       const float* __restrict__ Wfc,
                                                       const float* __restrict__ bfc,
                                                       float* __restrict__ out, int n) {
  int i = blockIdx.x * 4 + threadIdx.y;
  if (i >= n) return;
  int l = threadIdx.x;
  float v = fmaxf(acc[(size_t)i * 64 + l] + b[l], 0.0f) * Wfc[l];
#pragma unroll
  for (int off = 32; off > 0; off >>= 1) v += __shfl_down(v, off, 64);
  if (l == 0) out[i] = v + bfc[0];
}

struct Ctx {
  const int* row_ptr;
  const unsigned int* cw;
  const float* lamp;
  float* acc;
  int N;
  hipStream_t stream;
};

template <int F>
static void cheb_layer(const Ctx& c, const ushort* in, const float* W, ushort* t1b,
                       ushort* t2b, ushort* spare) {
  constexpr int RPB = 1024 / F;
  dim3 bs(F / 4, RPB);
  int gs = (c.N + RPB - 1) / RPB;
  spmv_fused<F, 0, true><<<gs, bs, 0, c.stream>>>(c.row_ptr, c.cw, c.lamp, in, nullptr, t1b,
                                                  c.acc, W, c.N);
  const ushort* t0 = in;
  ushort* t1 = t1b;
  ushort* fr = t2b;
  for (int k = 2; k < 7; ++k) {
    if (k < 6)
      spmv_fused<F, 1, true><<<gs, bs, 0, c.stream>>>(c.row_ptr, c.cw, c.lamp, t1, t0, fr,
                                                      c.acc, W + k * F * 64, c.N);
    else
      spmv_fused<F, 1, false><<<gs, bs, 0, c.stream>>>(c.row_ptr, c.cw, c.lamp, t1, t0, fr,
                                                       c.acc, W + k * F * 64, c.N);
    ushort* nfr = (k == 2) ? spare : (ushort*)t0;
    t0 = t1;
    t1 = fr;
    fr = nfr;
  }
}

extern "C" void kernel_launch(void* const* d_in, const int* in_sizes, int n_in, void* d_out,
                              int out_size, void* d_ws, size_t ws_size, hipStream_t stream) {
  const float* x = (const float*)d_in[0];
  const int* ei = (const int*)d_in[1];
  const float* lamp = (const float*)d_in[2];
  const float* W1 = (const float*)d_in[3];
  const float* b1 = (const float*)d_in[4];
  const float* W2 = (const float*)d_in[5];
  const float* b2 = (const float*)d_in[6];
  const float* W3 = (const float*)d_in[7];
  const float* b3 = (const float*)d_in[8];
  const float* Wfc = (const float*)d_in[9];
  const float* bfc = (const float*)d_in[10];

  const int N = in_sizes[0] / 16;  // 50000 (< 65536 required for cw packing)
  const int E = in_sizes[1] / 2;
  const int* row = ei;
  const int* col = ei + E;

  // ---- workspace carve ----
  char* p = (char*)d_ws;
  auto alloc = [&](size_t bytes) {
    char* r = p;
    p += WS_ALIGN(bytes);
    return r;
  };
  int* deg = (int*)alloc((size_t)N * 4);
  int* row_ptr = (int*)alloc((size_t)(N + 1) * 4);
  int* cursor = (int*)alloc((size_t)N * 4);
  unsigned int* cw = (unsigned int*)alloc((size_t)E * 4);
  float* dis = (float*)alloc((size_t)N * 4);
  int* bsum = (int*)alloc(256 * 4);
  ushort* xh = (ushort*)alloc((size_t)N * 16 * 2);
  ushort* A = (ushort*)alloc((size_t)N * 64 * 2);
  ushort* B = (ushort*)alloc((size_t)N * 64 * 2);
  ushort* C = (ushort*)alloc((size_t)N * 64 * 2);
  float* acc = (float*)alloc((size_t)N * 64 * 4);
  (void)ws_size;
  (void)n_in;
  (void)out_size;

  // ---- CSR build ----
  hipMemsetAsync(deg, 0, (size_t)N * 4, stream);
  hist_kernel<<<(E + 255) / 256, 256, 0, stream>>>(row, E, deg);
  int nb = (N + 1023) / 1024;  // <= 64 for N <= 65536
  scan_sum_kernel<<<nb, 256, 0, stream>>>(deg, bsum, N);
  scan_bsum_kernel<<<1, 64, 0, stream>>>(bsum, nb);
  scan_out_kernel<<<nb, 256, 0, stream>>>(deg, bsum, row_ptr, cursor, dis, N);
  scatter_kernel<<<(E + 255) / 256, 256, 0, stream>>>(row, col, E, cursor, dis, lamp, cw);

  // x -> fp16
  f32_to_f16_kernel<<<(N * 16 / 4 + 255) / 256, 256, 0, stream>>>(x, xh, N * 16 / 4);

  Ctx c{row_ptr, cw, lamp, acc, N, stream};

  // ---- layer 1 (F_IN=16): rotation buffers carved from C (3 x N*16 halves) ----
  ushort* C0 = C;
  ushort* C1 = C + (size_t)N * 16;
  ushort* C2 = C + (size_t)N * 32;
  cheb_layer<16>(c, xh, W1, C0, C1, C2);
  bias_relu_kernel<<<(N * 16 + 255) / 256, 256, 0, stream>>>(acc, b1, A, N * 16);

  // ---- layer 2 (64 -> 64): in=A, rotate over {B, C, A} ----
  cheb_layer<64>(c, A, W2, B, C, A);
  bias_relu_kernel<<<(N * 16 + 255) / 256, 256, 0, stream>>>(acc, b2, C, N * 16);

  // ---- layer 3 (64 -> 64): in=C, rotate over {A, B, C} ----
  cheb_layer<64>(c, C, W3, A, B, C);

  // ---- fused bias+relu+FC ----
  fc_fused_kernel<<<(N + 3) / 4, dim3(64, 4), 0, stream>>>(acc, b3, Wfc, bfc, (float*)d_out,
                                                           N);
}

// Round 5
// 454.707 us; speedup vs baseline: 3.9983x; 1.2464x over previous
//
#include <hip/hip_runtime.h>
#include <math.h>

// ---------------------------------------------------------------------------
// ChebNet: 3x ChebConv(S=7) + ReLU, then FC(64->1).
// N=50000 nodes, E=800000 edges, F_IN=16, H=64.
// R4: pure fp16 SpMV (no epilogue) writing Tx_k into concat buffer [N][7F];
// one MFMA GEMM per layer (Tx_cat @ W_cat, W pre-packed to fragment order,
// bias+relu fused). Removes the LDS-bound per-spmv GEMM epilogue.
// ---------------------------------------------------------------------------

#define WS_ALIGN(x) (((size_t)(x) + 255) & ~(size_t)255)

using f16x8 = __attribute__((ext_vector_type(8))) _Float16;
using f32x4 = __attribute__((ext_vector_type(4))) float;

__device__ inline float h2f_bits(unsigned int b) {
  unsigned short s = (unsigned short)(b & 0xffffu);
  _Float16 h;
  __builtin_memcpy(&h, &s, 2);
  return (float)h;
}
__device__ inline unsigned short f2h_bits(float f) {
  _Float16 h = (_Float16)f;
  unsigned short s;
  __builtin_memcpy(&s, &h, 2);
  return s;
}
union H4 {
  ushort4 u;
  _Float16 h[4];
};

__global__ __launch_bounds__(256) void hist_kernel(const int* __restrict__ row, int E,
                                                   int* __restrict__ deg) {
  int i = blockIdx.x * 256 + threadIdx.x;
  if (i < E) atomicAdd(&deg[row[i]], 1);
}

// ---- hierarchical scan ----
__global__ __launch_bounds__(256) void scan_sum_kernel(const int* __restrict__ deg,
                                                       int* __restrict__ bsum, int n) {
  int base = blockIdx.x * 1024 + threadIdx.x;
  int v = 0;
#pragma unroll
  for (int u = 0; u < 4; ++u) {
    int i = base + u * 256;
    if (i < n) v += deg[i];
  }
#pragma unroll
  for (int off = 32; off > 0; off >>= 1) v += __shfl_down(v, off, 64);
  __shared__ int ws[4];
  int lane = threadIdx.x & 63, wave = threadIdx.x >> 6;
  if (lane == 0) ws[wave] = v;
  __syncthreads();
  if (threadIdx.x == 0) bsum[blockIdx.x] = ws[0] + ws[1] + ws[2] + ws[3];
}

__global__ __launch_bounds__(64) void scan_bsum_kernel(int* __restrict__ bsum, int nb) {
  int t = threadIdx.x;
  int v = (t < nb) ? bsum[t] : 0;
  int sc = v;
#pragma unroll
  for (int off = 1; off < 64; off <<= 1) {
    int tv = __shfl_up(sc, off, 64);
    if (t >= off) sc += tv;
  }
  if (t < nb) bsum[t] = sc - v;
}

__global__ __launch_bounds__(256) void scan_out_kernel(const int* __restrict__ deg,
                                                       const int* __restrict__ bsum,
                                                       int* __restrict__ row_ptr,
                                                       int* __restrict__ cursor,
                                                       float* __restrict__ dis, int n) {
  int base = blockIdx.x * 1024 + threadIdx.x * 4;
  int loc[4];
  int s = 0;
#pragma unroll
  for (int u = 0; u < 4; ++u) {
    int i = base + u;
    loc[u] = (i < n) ? deg[i] : 0;
    s += loc[u];
  }
  int lane = threadIdx.x & 63, wave = threadIdx.x >> 6;
  int sc = s;
#pragma unroll
  for (int off = 1; off < 64; off <<= 1) {
    int tv = __shfl_up(sc, off, 64);
    if (lane >= off) sc += tv;
  }
  __shared__ int wtot[4];
  if (lane == 63) wtot[wave] = sc;
  __syncthreads();
  int pre = sc - s + bsum[blockIdx.x];
  for (int w = 0; w < wave; ++w) pre += wtot[w];
  if (blockIdx.x == 0 && threadIdx.x == 0) row_ptr[0] = 0;
  int running = pre;
#pragma unroll
  for (int u = 0; u < 4; ++u) {
    int i = base + u;
    if (i < n) {
      cursor[i] = running;
      dis[i] = (loc[u] > 0) ? (1.0f / sqrtf((float)loc[u])) : 0.0f;
      running += loc[u];
      row_ptr[i + 1] = running;
    }
  }
}

// cw entry: (col << 16) | fp16_bits(w).  Requires N < 65536.
__global__ __launch_bounds__(256) void scatter_kernel(const int* __restrict__ row,
                                                      const int* __restrict__ col, int E,
                                                      int* __restrict__ cursor,
                                                      const float* __restrict__ dis,
                                                      const float* __restrict__ lamp,
                                                      unsigned int* __restrict__ cw) {
  int i = blockIdx.x * 256 + threadIdx.x;
  if (i >= E) return;
  int r = row[i], c = col[i];
  int pos = atomicAdd(&cursor[r], 1);
  float w = -(2.0f / lamp[0]) * dis[r] * dis[c];
  cw[pos] = ((unsigned int)c << 16) | (unsigned int)f2h_bits(w);
}

// x (N x 16 fp32) -> T1 slot0 (stride 128 halves) + zero the pad slot [112,128)
__global__ __launch_bounds__(256) void x_to_t1_kernel(const float* __restrict__ x,
                                                      ushort* __restrict__ T1, int n) {
  int j = blockIdx.x * 256 + threadIdx.x;
  if (j >= n * 8) return;
  int row = j >> 3, s = j & 7;
  if (s < 4) {
    float4 v = ((const float4*)x)[(size_t)row * 4 + s];
    ushort4 o;
    o.x = f2h_bits(v.x);
    o.y = f2h_bits(v.y);
    o.z = f2h_bits(v.z);
    o.w = f2h_bits(v.w);
    ((ushort4*)T1)[(size_t)row * 32 + s] = o;
  } else {
    ((ushort4*)T1)[(size_t)row * 32 + 28 + (s - 4)] = make_ushort4(0, 0, 0, 0);
  }
}

// Pack W ([KREAL][64] f32, zero-padded to KT*32) into MFMA B-fragment order:
// Wpk[((kt*4+nt)*64 + lane)*8 + j] = f16( W[kt*32 + (lane>>4)*8 + j][nt*16 + (lane&15)] )
template <int KREAL, int KT>
__global__ __launch_bounds__(256) void wpk_prep(const float* __restrict__ W,
                                                ushort* __restrict__ Wpk) {
  int t = blockIdx.x * 256 + threadIdx.x;
  if (t >= KT * 256) return;
  int kt = t >> 8, nt = (t >> 6) & 3, l = t & 63;
  int col = nt * 16 + (l & 15);
  int kb = kt * 32 + ((l >> 4) << 3);
  ushort tmp[8];
#pragma unroll
  for (int j = 0; j < 8; ++j) {
    int k = kb + j;
    float v = (k < KREAL) ? W[(size_t)k * 64 + col] : 0.0f;
    tmp[j] = f2h_bits(v);
  }
  ushort4* dst = (ushort4*)Wpk + (size_t)((kt * 4 + nt) * 64 + l) * 2;
  dst[0] = make_ushort4(tmp[0], tmp[1], tmp[2], tmp[3]);
  dst[1] = make_ushort4(tmp[4], tmp[5], tmp[6], tmp[7]);
}

// ---------------------------------------------------------------------------
// Pure SpMV, fp16 in/out, fp32 math.  All pointers pre-offset to the slot;
// row stride S4 (ushort4 units) is compile-time.
// MODE 0: out = spmv(xin);  MODE 1: out = 2*spmv(xin) - sub
// ---------------------------------------------------------------------------
template <int F, int MODE, int S4>
__global__ __launch_bounds__(256) void spmv_pure(const int* __restrict__ row_ptr,
                                                 const unsigned int* __restrict__ cw,
                                                 const float* __restrict__ lamp,
                                                 const ushort4* __restrict__ xin,
                                                 const ushort4* __restrict__ sub,
                                                 ushort4* __restrict__ xout, int n) {
  constexpr int LPR = F / 4;      // lanes per row
  constexpr int RPB = 256 / LPR;  // rows per block
  constexpr int EPL = 16 / LPR;   // cw entries per lane per 16-edge batch
  int i = blockIdx.x * RPB + threadIdx.y;
  if (i >= n) return;
  int f4 = threadIdx.x;
  int lane = (threadIdx.y * LPR + f4) & 63;
  int grpbase = lane - f4;
  float diag = 2.0f / lamp[0] - 1.0f;
  H4 xd;
  xd.u = xin[(size_t)i * S4 + f4];
  float4 a = make_float4(diag * (float)xd.h[0], diag * (float)xd.h[1],
                         diag * (float)xd.h[2], diag * (float)xd.h[3]);
  int s = row_ptr[i], e = row_ptr[i + 1];

  for (int j0 = s; j0 < e; j0 += 16) {
    unsigned int pv[EPL];
#pragma unroll
    for (int u = 0; u < EPL; ++u) {
      int jj = j0 + f4 * EPL + u;
      pv[u] = cw[jj < e ? jj : (e - 1)];
    }
    H4 xv[16];
    float ww[16];
#pragma unroll
    for (int u = 0; u < 16; ++u) {
      unsigned int pu = (unsigned int)__shfl((int)pv[u % EPL], grpbase + u / EPL, 64);
      bool valid = (j0 + u) < e;
      ww[u] = valid ? h2f_bits(pu) : 0.0f;
      int ad = valid ? (int)(pu >> 16) : i;
      xv[u].u = xin[(size_t)ad * S4 + f4];
    }
#pragma unroll
    for (int u = 0; u < 16; ++u) {
      a.x += ww[u] * (float)xv[u].h[0];
      a.y += ww[u] * (float)xv[u].h[1];
      a.z += ww[u] * (float)xv[u].h[2];
      a.w += ww[u] * (float)xv[u].h[3];
    }
  }

  float4 r;
  if (MODE == 1) {
    H4 sv;
    sv.u = sub[(size_t)i * S4 + f4];
    r = make_float4(2.0f * a.x - (float)sv.h[0], 2.0f * a.y - (float)sv.h[1],
                    2.0f * a.z - (float)sv.h[2], 2.0f * a.w - (float)sv.h[3]);
  } else {
    r = a;
  }
  ushort4 o;
  o.x = f2h_bits(r.x);
  o.y = f2h_bits(r.y);
  o.z = f2h_bits(r.z);
  o.w = f2h_bits(r.w);
  xout[(size_t)i * S4 + f4] = o;
}

// ---------------------------------------------------------------------------
// MFMA GEMM: D[N x 64] = A[N x KT*32] @ Wcat + bias, relu -> fp16 strided dst
// (or raw fp32 acc for the last layer).  One wave = 16-row tile; B-frags read
// directly from pre-packed Wpk (coalesced, L2-resident); no LDS.
// mfma_f32_16x16x32_f16: A[l&15][(l>>4)*8+j]; B[(l>>4)*8+j][l&15];
// D row=(l>>4)*4+reg, col=l&15 (m89-verified).
// ---------------------------------------------------------------------------
template <int KT, bool LAST>
__global__ __launch_bounds__(256) void gemm_mfma(const ushort* __restrict__ A,
                                                 const ushort* __restrict__ Wpk,
                                                 const float* __restrict__ bias,
                                                 ushort* __restrict__ dsth, int dstride,
                                                 float* __restrict__ dacc, int n) {
  int l = threadIdx.x & 63;
  int tile = blockIdx.x * 4 + (threadIdx.x >> 6);
  int r0 = tile * 16;
  if (r0 >= n) return;
  constexpr int ASTR = KT * 32;
  const f16x8* ap = (const f16x8*)(A + (size_t)(r0 + (l & 15)) * ASTR + ((l >> 4) << 3));
  const f16x8* bp = (const f16x8*)Wpk + l;
  f32x4 c[4] = {{0.f, 0.f, 0.f, 0.f},
                {0.f, 0.f, 0.f, 0.f},
                {0.f, 0.f, 0.f, 0.f},
                {0.f, 0.f, 0.f, 0.f}};
#pragma unroll
  for (int kt = 0; kt < KT; ++kt) {
    f16x8 af = ap[kt * 4];
#pragma unroll
    for (int nt = 0; nt < 4; ++nt) {
      f16x8 bf = bp[(kt * 4 + nt) * 64];
      c[nt] = __builtin_amdgcn_mfma_f32_16x16x32_f16(af, bf, c[nt], 0, 0, 0);
    }
  }
  int rb = r0 + ((l >> 4) << 2);
  int cc = l & 15;
#pragma unroll
  for (int nt = 0; nt < 4; ++nt) {
    int col = nt * 16 + cc;
    if (LAST) {
#pragma unroll
      for (int j = 0; j < 4; ++j) dacc[(size_t)(rb + j) * 64 + col] = c[nt][j];
    } else {
      float bv = bias[col];
#pragma unroll
      for (int j = 0; j < 4; ++j) {
        float v = fmaxf(c[nt][j] + bv, 0.0f);
        dsth[(size_t)(rb + j) * dstride + col] = f2h_bits(v);
      }
    }
  }
}

// layer-3 epilogue: out[i] = sum_h relu(acc[i,h]+b[h]) * Wfc[h] + bfc
__global__ __launch_bounds__(256) void fc_fused_kernel(const float* __restrict__ acc,
                                                       const float* __restrict__ b,
                                                       const float* __restrict__ Wfc,
                                                       const float* __restrict__ bfc,
                                                       float* __restrict__ out, int n) {
  int i = blockIdx.x * 4 + threadIdx.y;
  if (i >= n) return;
  int l = threadIdx.x;
  float v = fmaxf(acc[(size_t)i * 64 + l] + b[l], 0.0f) * Wfc[l];
#pragma unroll
  for (int off = 32; off > 0; off >>= 1) v += __shfl_down(v, off, 64);
  if (l == 0) out[i] = v + bfc[0];
}

extern "C" void kernel_launch(void* const* d_in, const int* in_sizes, int n_in, void* d_out,
                              int out_size, void* d_ws, size_t ws_size, hipStream_t stream) {
  const float* x = (const float*)d_in[0];
  const int* ei = (const int*)d_in[1];
  const float* lamp = (const float*)d_in[2];
  const float* W1 = (const float*)d_in[3];
  const float* b1 = (const float*)d_in[4];
  const float* W2 = (const float*)d_in[5];
  const float* b2 = (const float*)d_in[6];
  const float* W3 = (const float*)d_in[7];
  const float* b3 = (const float*)d_in[8];
  const float* Wfc = (const float*)d_in[9];
  const float* bfc = (const float*)d_in[10];

  const int N = in_sizes[0] / 16;  // 50000 (< 65536 required for cw packing)
  const int E = in_sizes[1] / 2;
  const int* row = ei;
  const int* col = ei + E;

  // ---- workspace carve ----
  char* p = (char*)d_ws;
  auto alloc = [&](size_t bytes) {
    char* r = p;
    p += WS_ALIGN(bytes);
    return r;
  };
  int* deg = (int*)alloc((size_t)N * 4);
  int* row_ptr = (int*)alloc((size_t)(N + 1) * 4);
  int* cursor = (int*)alloc((size_t)N * 4);
  unsigned int* cw = (unsigned int*)alloc((size_t)E * 4);
  float* dis = (float*)alloc((size_t)N * 4);
  int* bsum = (int*)alloc(256 * 4);
  ushort* T1 = (ushort*)alloc((size_t)N * 128 * 2);   // layer-1 concat [N][128] (pad 112..127)
  ushort* TXC = (ushort*)alloc((size_t)N * 448 * 2);  // layers 2/3 concat [N][448]
  float* acc = (float*)alloc((size_t)N * 64 * 4);
  ushort* Wpk1 = (ushort*)alloc((size_t)4 * 256 * 8 * 2);
  ushort* Wpk2 = (ushort*)alloc((size_t)14 * 256 * 8 * 2);
  ushort* Wpk3 = (ushort*)alloc((size_t)14 * 256 * 8 * 2);
  (void)ws_size;
  (void)n_in;
  (void)out_size;

  // ---- CSR build ----
  hipMemsetAsync(deg, 0, (size_t)N * 4, stream);
  hist_kernel<<<(E + 255) / 256, 256, 0, stream>>>(row, E, deg);
  int nb = (N + 1023) / 1024;  // <= 64 for N <= 65536
  scan_sum_kernel<<<nb, 256, 0, stream>>>(deg, bsum, N);
  scan_bsum_kernel<<<1, 64, 0, stream>>>(bsum, nb);
  scan_out_kernel<<<nb, 256, 0, stream>>>(deg, bsum, row_ptr, cursor, dis, N);
  scatter_kernel<<<(E + 255) / 256, 256, 0, stream>>>(row, col, E, cursor, dis, lamp, cw);

  // ---- weight packing + input conversion ----
  x_to_t1_kernel<<<(N * 8 + 255) / 256, 256, 0, stream>>>(x, T1, N);
  wpk_prep<112, 4><<<4, 256, 0, stream>>>(W1, Wpk1);
  wpk_prep<448, 14><<<14, 256, 0, stream>>>(W2, Wpk2);
  wpk_prep<448, 14><<<14, 256, 0, stream>>>(W3, Wpk3);

  // ---- layer 1 (F=16, concat stride 128 halves = 32 ushort4, slot k at +4k) ----
  {
    ushort4* B = (ushort4*)T1;
    dim3 bs(4, 64);
    int gs = (N + 63) / 64;
    spmv_pure<16, 0, 32><<<gs, bs, 0, stream>>>(row_ptr, cw, lamp, B + 0, nullptr, B + 4, N);
    for (int k = 2; k < 7; ++k)
      spmv_pure<16, 1, 32><<<gs, bs, 0, stream>>>(row_ptr, cw, lamp, B + 4 * (k - 1),
                                                  B + 4 * (k - 2), B + 4 * k, N);
    gemm_mfma<4, false><<<(N / 16 + 3) / 4 + 1, 256, 0, stream>>>(T1, Wpk1, b1, TXC, 448,
                                                                  nullptr, N);
  }

  // ---- layers 2,3 (F=64, concat stride 448 halves = 112 ushort4, slot k at +16k) ----
  for (int layer = 2; layer <= 3; ++layer) {
    ushort4* B = (ushort4*)TXC;
    dim3 bs(16, 16);
    int gs = (N + 15) / 16;
    spmv_pure<64, 0, 112><<<gs, bs, 0, stream>>>(row_ptr, cw, lamp, B + 0, nullptr, B + 16, N);
    for (int k = 2; k < 7; ++k)
      spmv_pure<64, 1, 112><<<gs, bs, 0, stream>>>(row_ptr, cw, lamp, B + 16 * (k - 1),
                                                   B + 16 * (k - 2), B + 16 * k, N);
    if (layer == 2)
      gemm_mfma<14, false><<<(N / 16 + 3) / 4 + 1, 256, 0, stream>>>(TXC, Wpk2, b2, TXC, 448,
                                                                     nullptr, N);
    else
      gemm_mfma<14, true><<<(N / 16 + 3) / 4 + 1, 256, 0, stream>>>(TXC, Wpk3, nullptr,
                                                                    nullptr, 0, acc, N);
  }

  // ---- fused bias+relu+FC ----
  fc_fused_kernel<<<(N + 3) / 4, dim3(64, 4), 0, stream>>>(acc, b3, Wfc, bfc, (float*)d_out,
                                                           N);
}